// Round 5
// baseline (175.612 us; speedup 1.0000x reference)
//
#include <hip/hip_runtime.h>
#include <stdint.h>

// ContrastiveLoss: mean over all pairs of (same-label ? d2 : relu(1-dist)^2)
// z: [8192,128] fp32, labels: [8192] int32. Output: 1 fp32 scalar.
//
// R5: latency-bound fix. 256-thread blocks (4 waves, 4x4 frags each) with
// VGPR<=128 (__launch_bounds__(256,4)) -> 4 independent blocks/CU (was 2)
// for 4 overlapping stage->barrier->compute streams. Branchless epilogue
// with ONE deferred wave-vote (min-accumulate all 64 outputs, slow-path
// redo only if any d2<1 -- diagonal-touching waves only). Final reduction
// folded into loss via device-scope ticket (last block sums partials);
// reduce_kernel launch eliminated.

#define NROWS 8192
#define DIMK  128
#define NB    64                     // 8192 / 128
#define NBLK  (NB * (NB + 1) / 2)    // 2080 upper-triangle blocks

typedef __attribute__((ext_vector_type(4))) float f32x4;
typedef __attribute__((ext_vector_type(2))) long long2v;

#define AS_GLOBAL __attribute__((address_space(1)))
#define AS_LDS    __attribute__((address_space(3)))

// Convert z -> fp8 e4m3, k-permuted rows (granule (q,ks): byte p =
// q*32+ks*8+(k&7) for logical k; dot-product-invariant), + per-row sum of
// squares of the ROUNDED values (keeps diagonal d2 ~= 0). Zeroes the ticket.
__global__ __launch_bounds__(256) void prep_kernel(
    const float* __restrict__ z, unsigned char* __restrict__ zb,
    float* __restrict__ sq, unsigned int* __restrict__ counter) {
  if (blockIdx.x == 0 && threadIdx.x == 0) *counter = 0;
  int tid = threadIdx.x;
  int row = (blockIdx.x << 3) + (tid >> 5);          // 8 rows per block
  int c32 = tid & 31;                                // 32 lanes per row
  float4 x = ((const float4*)(z + (size_t)row * DIMK))[c32];
  int u = __builtin_amdgcn_cvt_pk_fp8_f32(x.x, x.y, 0, false);
  u     = __builtin_amdgcn_cvt_pk_fp8_f32(x.z, x.w, u, true);
  float r0 = __builtin_amdgcn_cvt_f32_fp8(u, 0);
  float r1 = __builtin_amdgcn_cvt_f32_fp8(u, 1);
  float r2 = __builtin_amdgcn_cvt_f32_fp8(u, 2);
  float r3 = __builtin_amdgcn_cvt_f32_fp8(u, 3);
  float s = (r0 * r0 + r1 * r1) + (r2 * r2 + r3 * r3);
  int k0 = c32 << 2;                                 // logical k of byte 0
  int p = (((k0 >> 3) & 3) << 5) + ((k0 >> 5) << 3) + (k0 & 7);  // 4B-aligned
  *(uint32_t*)(zb + (size_t)row * DIMK + p) = (uint32_t)u;
  #pragma unroll
  for (int off = 16; off; off >>= 1) s += __shfl_down(s, off, 32);
  if (c32 == 0) sq[row] = s;
}

// One block = one 128x128 tile of z.z^T, upper triangle, off-diag weight 2x.
// 256 threads = 4 waves (2x2); each wave 4x4 frags of 16x16x32 fp8_fp8.
// Tiles 16KB each (128B rows, 8 chunks), XOR-8 chunk swizzle, staged once.
__global__ __launch_bounds__(256, 4) void loss_kernel(
    const unsigned char* __restrict__ zb, const float* __restrict__ sq,
    const int* __restrict__ labels, float* __restrict__ partials,
    unsigned int* __restrict__ counter, float* __restrict__ out) {
  __shared__ __align__(16) unsigned char ldsA[16384];
  __shared__ __align__(16) unsigned char ldsB[16384];
  __shared__ __align__(16) float sqAl[128];
  __shared__ __align__(16) float sqBl[128];
  __shared__ __align__(16) int   laAl[128];
  __shared__ __align__(16) int   laBl[128];
  __shared__ float red[4];
  __shared__ int lastFlag;

  int tid = threadIdx.x, lane = tid & 63, wave = tid >> 6;

  // ---- triangular decode: bid -> (bi, bj), bi <= bj ----
  int bid = blockIdx.x;
  #define TRI(rr) ((rr) * NB - ((rr) * ((rr) - 1)) / 2)
  int r = (int)(((float)(2 * NB + 1) -
                 sqrtf((float)((2 * NB + 1) * (2 * NB + 1) - 8 * bid))) * 0.5f);
  if (r < 0) r = 0; if (r > NB - 1) r = NB - 1;
  while (TRI(r + 1) <= bid) ++r;
  while (TRI(r) > bid) --r;
  int bi = r, bj = bid - TRI(r) + r;

  // ---- stage tiles: 1024 16B-chunks per tile, 256 lanes -> 4 rounds ----
  const unsigned char* Ab = zb + (((size_t)bi << 7) * DIMK);
  const unsigned char* Bb = zb + (((size_t)bj << 7) * DIMK);
  #pragma unroll
  for (int t = 0; t < 4; ++t) {
    int L0 = (t << 8) + (wave << 6);                 // wave-uniform chunk base
    int L  = L0 + lane;
    int rw = L >> 3;                                 // tile row (8 chunks/row)
    int c  = (L & 7) ^ (rw & 7);                     // swizzled source chunk
    __builtin_amdgcn_global_load_lds(
        (const AS_GLOBAL void*)(uintptr_t)(Ab + rw * DIMK + (c << 4)),
        (AS_LDS void*)(uintptr_t)(ldsA + (size_t)L0 * 16), 16, 0, 0);
    __builtin_amdgcn_global_load_lds(
        (const AS_GLOBAL void*)(uintptr_t)(Bb + rw * DIMK + (c << 4)),
        (AS_LDS void*)(uintptr_t)(ldsB + (size_t)L0 * 16), 16, 0, 0);
  }
  // ---- stage sq + labels for this block's rows/cols into LDS ----
  if (tid < 128) {
    sqAl[tid] = sq[(bi << 7) + tid];
    laAl[tid] = labels[(bi << 7) + tid];
  } else {
    int t2 = tid & 127;
    sqBl[t2] = sq[(bj << 7) + t2];
    laBl[t2] = labels[(bj << 7) + t2];
  }
  asm volatile("s_waitcnt vmcnt(0)" ::: "memory");
  __syncthreads();

  // ---- MFMA: k-pair-split loads keep live regs low (acc 64 + frags 32) ----
  int wm = wave >> 1, wn = wave & 1;
  int lc = lane & 15;                                // frag row (A) / col (out)
  int q  = lane >> 4;                                // quad: k-granule select
  int x7 = lc & 7;
  f32x4 acc[4][4] = {};
  #pragma unroll
  for (int kp = 0; kp < 2; ++kp) {
    // chunk (2q+kp)^x7 of each operand row holds ks = {2kp, 2kp+1}
    long2v a[4], b[4];
    #pragma unroll
    for (int i = 0; i < 4; ++i)
      a[i] = *(const long2v*)(ldsA + ((wm << 6) + (i << 4) + lc) * 128 +
                              ((((q << 1) + kp) ^ x7) << 4));
    #pragma unroll
    for (int j = 0; j < 4; ++j)
      b[j] = *(const long2v*)(ldsB + ((wn << 6) + (j << 4) + lc) * 128 +
                              ((((q << 1) + kp) ^ x7) << 4));
    #pragma unroll
    for (int i = 0; i < 4; ++i)
      #pragma unroll
      for (int j = 0; j < 4; ++j)
        acc[i][j] = __builtin_amdgcn_mfma_f32_16x16x32_fp8_fp8(
            a[i].x, b[j].x, acc[i][j], 0, 0, 0);
    #pragma unroll
    for (int i = 0; i < 4; ++i)
      #pragma unroll
      for (int j = 0; j < 4; ++j)
        acc[i][j] = __builtin_amdgcn_mfma_f32_16x16x32_fp8_fp8(
            a[i].y, b[j].y, acc[i][j], 0, 0, 0);
  }

  // ---- epilogue: branchless fast pass + ONE deferred vote ----
  // C/D layout (shape-determined): col = lane&15, row = (lane>>4)*4 + reg.
  // If every d2 in this wave's 64 outputs >= 1, the non-eq term is EXACTLY 0
  // and the eq term is exactly d2. Otherwise (diagonal-touching waves only)
  // redo everything on the exact slow path.
  int r0 = q << 2;
  float sn_[4]; int ln_[4];
  #pragma unroll
  for (int j = 0; j < 4; ++j) {
    int n = (wn << 6) + (j << 4) + lc;
    sn_[j] = sqBl[n]; ln_[j] = laBl[n];
  }
  float ps0 = 0.f, ps1 = 0.f, ps2 = 0.f, ps3 = 0.f;
  float mnall = 1e30f;
  #pragma unroll
  for (int i = 0; i < 4; ++i) {
    int mb = (wm << 6) + (i << 4) + r0;
    f32x4 sm4 = *(const f32x4*)&sqAl[mb];
    int4  lm4 = *(const int4*)&laAl[mb];
    #pragma unroll
    for (int j = 0; j < 4; ++j) {
      float d0  = fmaf(-2.f, acc[i][j][0], sm4[0] + sn_[j]);
      float d1  = fmaf(-2.f, acc[i][j][1], sm4[1] + sn_[j]);
      float d2_ = fmaf(-2.f, acc[i][j][2], sm4[2] + sn_[j]);
      float d3  = fmaf(-2.f, acc[i][j][3], sm4[3] + sn_[j]);
      mnall = fminf(mnall, fminf(fminf(d0, d1), fminf(d2_, d3)));
      ps0 += (lm4.x == ln_[j]) ? d0  : 0.f;
      ps1 += (lm4.y == ln_[j]) ? d1  : 0.f;
      ps2 += (lm4.z == ln_[j]) ? d2_ : 0.f;
      ps3 += (lm4.w == ln_[j]) ? d3  : 0.f;
    }
  }
  if (__builtin_expect(__any(mnall < 1.f), 0)) {
    // exact slow path: recompute all 64 outputs (acc still live)
    ps0 = ps1 = ps2 = ps3 = 0.f;
    #pragma unroll
    for (int i = 0; i < 4; ++i) {
      int mb = (wm << 6) + (i << 4) + r0;
      f32x4 sm4 = *(const f32x4*)&sqAl[mb];
      int4  lm4 = *(const int4*)&laAl[mb];
      #pragma unroll
      for (int j = 0; j < 4; ++j) {
        float dc, t;
        dc = fmaxf(fmaf(-2.f, acc[i][j][0], sm4[0] + sn_[j]), 0.f);
        t = fmaxf(1.f - sqrtf(dc), 0.f);
        ps0 += (lm4.x == ln_[j]) ? dc : t * t;
        dc = fmaxf(fmaf(-2.f, acc[i][j][1], sm4[1] + sn_[j]), 0.f);
        t = fmaxf(1.f - sqrtf(dc), 0.f);
        ps1 += (lm4.y == ln_[j]) ? dc : t * t;
        dc = fmaxf(fmaf(-2.f, acc[i][j][2], sm4[2] + sn_[j]), 0.f);
        t = fmaxf(1.f - sqrtf(dc), 0.f);
        ps2 += (lm4.z == ln_[j]) ? dc : t * t;
        dc = fmaxf(fmaf(-2.f, acc[i][j][3], sm4[3] + sn_[j]), 0.f);
        t = fmaxf(1.f - sqrtf(dc), 0.f);
        ps3 += (lm4.w == ln_[j]) ? dc : t * t;
      }
    }
  }
  float psum = (ps0 + ps1) + (ps2 + ps3);
  float w = (bi == bj) ? 1.f : 2.f;                  // symmetry weight
  psum *= w * (1.f / (8192.f * 8192.f));             // 2^-26, exact

  // ---- block reduction -> partials[bid], ticket, last block sums all ----
  #pragma unroll
  for (int off = 32; off; off >>= 1) psum += __shfl_down(psum, off);
  if (lane == 0) red[wave] = psum;
  __syncthreads();
  if (tid == 0) {
    partials[bid] = (red[0] + red[1]) + (red[2] + red[3]);
    __threadfence();                                 // partial visible first
    unsigned int tk = atomicAdd(counter, 1u);        // device-scope
    lastFlag = (tk == NBLK - 1);
  }
  __syncthreads();
  if (lastFlag) {
    __threadfence();                                 // acquire others' stores
    float s = 0.f;
    for (int k = tid; k < NBLK; k += 256) s += partials[k];
    #pragma unroll
    for (int off = 32; off; off >>= 1) s += __shfl_down(s, off);
    if (lane == 0) red[wave] = s;
    __syncthreads();
    if (tid == 0) out[0] = (red[0] + red[1]) + (red[2] + red[3]);
  }
}

extern "C" void kernel_launch(void* const* d_in, const int* in_sizes, int n_in,
                              void* d_out, int out_size, void* d_ws, size_t ws_size,
                              hipStream_t stream) {
  const float* z      = (const float*)d_in[0];
  const int*   labels = (const int*)d_in[1];
  float*       out    = (float*)d_out;
  unsigned char* zb   = (unsigned char*)d_ws;                        // 1 MB
  char* p = (char*)d_ws + (size_t)NROWS * DIMK;
  float* sq             = (float*)p;                                 // 32 KB
  float* partials       = (float*)(p + NROWS * 4);                   // ~8 KB
  unsigned int* counter = (unsigned int*)(p + NROWS * 4 + NBLK * 4);

  prep_kernel<<<NROWS / 8, 256, 0, stream>>>(z, zb, sq, counter);
  loss_kernel<<<NBLK, 256, 0, stream>>>(zb, sq, labels, partials, counter, out);
}